// Round 9
// baseline (194.825 us; speedup 1.0000x reference)
//
#include <hip/hip_runtime.h>
#include <stdint.h>

#define B_ 4
#define C_ 256
#define H_ 64
#define W_ 64
#define O_ 256
#define K_ 9
#define CK 2304     // K_*C_  (ck = k*256 + c, k-major)
#define HW 4096
#define NTOT 16384  // B_*HW

typedef __bf16 bf16x8 __attribute__((ext_vector_type(8)));
typedef __bf16 bf16x4 __attribute__((ext_vector_type(4)));
typedef float f32x4 __attribute__((ext_vector_type(4)));
typedef float f32x2 __attribute__((ext_vector_type(2)));
typedef f32x2 __attribute__((aligned(4))) f32x2u;

__device__ __forceinline__ uint16_t f2bf(float f) {
  uint32_t u = __builtin_bit_cast(uint32_t, f);
  return (uint16_t)((u + 0x7FFFu + ((u >> 16) & 1u)) >> 16);
}

__device__ __forceinline__ uint32_t pk_bf16(float a, float b) {
  uint16_t lo = __builtin_bit_cast(uint16_t, (__bf16)a);
  uint16_t hi = __builtin_bit_cast(uint16_t, (__bf16)b);
  return (uint32_t)lo | ((uint32_t)hi << 16);
}

// ======== kA: fused prep — wb (2304 blk) | womb (288 blk) | xT transpose (1024 blk) ====
__global__ void kA_prep(const float* __restrict__ weight, const float* __restrict__ w_om,
                        const float* __restrict__ x, uint16_t* __restrict__ wb,
                        uint16_t* __restrict__ womb, uint16_t* __restrict__ xT) {
  int bx = blockIdx.x;
  int t = threadIdx.x;
  if (bx < 2304) {
    int idx = bx * 256 + t;
    int o = idx / CK;
    int rem = idx - o * CK;
    int k = rem >> 8, c = rem & 255;
    wb[idx] = f2bf(weight[(o * C_ + c) * K_ + k]);
  } else if (bx < 2592) {
    int idx = (bx - 2304) * 256 + t;
    int j = idx / CK;
    int ck = idx - j * CK;
    int k = ck >> 8, c = ck & 255;
    womb[idx] = (j < 27) ? f2bf(w_om[(j * 256 + c) * 9 + k]) : (uint16_t)0;
  } else {
    int bxl = bx - 2592;
    int ct = bxl & 3;
    int hwt = (bxl >> 2) & 63;
    int b = bxl >> 8;
    int l = t & 63;
    int cq = t >> 6;

    __shared__ __align__(16) uint16_t tile[64 * 72];

    const float* xb = x + ((b * 256 + ct * 64) * HW) + hwt * 64;
#pragma unroll
    for (int i = 0; i < 16; ++i) {
      int c = cq * 16 + i;
      tile[l * 72 + c] = f2bf(xb[c * HW + l]);
    }
    __syncthreads();

    int hw = t >> 2;
    int c8 = (t & 3) * 8;
    uint16_t* dst = xT + ((size_t)b << 20) + (size_t)(hwt * 64 + hw) * 256 + ct * 64;
    *(uint4*)&dst[c8] = *(const uint4*)&tile[hw * 72 + c8];
    *(uint4*)&dst[c8 + 32] = *(const uint4*)&tile[hw * 72 + c8 + 32];
  }
}

// ======== kFused: offset-conv + bilinear gather + main GEMM, one kernel ========
// Grid = 512 n-tiles of 32, block = 512 threads (8 waves). BM=256 (full M) means
// each cols row is produced once, in LDS, never touching global.
// Phase 0 (waves 0-3): om[32j][32n] MFMA -> bias/sigmoid -> ppm LDS.
// Main loop k=0..8 (double-buffered Bs): gather k+1 while MFMA k; 1 barrier/k.
__global__ void kFused(const uint16_t* __restrict__ wb, const uint16_t* __restrict__ womb,
                       const uint16_t* __restrict__ xT, const float* __restrict__ b_om,
                       const float* __restrict__ bias, float* __restrict__ out) {
  int nt = blockIdx.x;           // 0..511
  int n0 = nt * 32;
  int t = threadIdx.x;
  int lane = t & 63;
  int wv = __builtin_amdgcn_readfirstlane(t >> 6);  // 0..7
  int lr = lane & 15, q = lane >> 4;

  __shared__ float ppmL[3 * 9 * 32];                  // [s][k][nloc]
  __shared__ __align__(16) uint16_t Bs2[2][32 * 264]; // [buf][nloc][c], pad->264

  // ---------- phase 0: offset conv for this block's 32 n ----------
  if (wv < 4) {
    int ntile2 = wv & 1;         // n-sub tile of 16
    int jhalf = (wv >> 1) & 1;   // j-range 0..15 / 16..31
    int n = n0 + ntile2 * 16 + lr;
    int b = n >> 12;
    int hw = n & 4095;
    int y = hw >> 6, xx = hw & 63;
    const uint16_t* xb = xT + ((size_t)b << 20);
    const uint16_t* zrow = womb + 31 * CK;  // 2304 zeros
    f32x4 acc = {0.f, 0.f, 0.f, 0.f};
#pragma unroll
    for (int k = 0; k < 9; ++k) {
      int dy = k / 3, dx = k - dy * 3;
      int ny = y + dy - 1, nx = xx + dx - 1;
      bool valid = ((unsigned)ny < 64u) && ((unsigned)nx < 64u);
      int row = (min(max(ny, 0), 63) << 6) + min(max(nx, 0), 63);
      const uint16_t* bp = valid ? (xb + row * 256 + q * 8) : (zrow + q * 8);
      const uint16_t* ap = womb + (jhalf * 16 + lr) * CK + k * 256 + q * 8;
#pragma unroll
      for (int kt = 0; kt < 8; ++kt) {
        int c0 = kt * 32;
        acc = __builtin_amdgcn_mfma_f32_16x16x32_bf16(
            *(const bf16x8*)&ap[c0], *(const bf16x8*)&bp[c0], acc, 0, 0, 0);
      }
    }
#pragma unroll
    for (int r = 0; r < 4; ++r) {
      int j = jhalf * 16 + q * 4 + r;
      if (j < 27) {
        float s = acc[r] + b_om[j];
        int nloc = ntile2 * 16 + lr;
        if (j < 18) {
          int k2 = j >> 1;
          if ((j & 1) == 0)
            ppmL[(0 * 9 + k2) * 32 + nloc] = (float)(y - 1 + k2 / 3) + s;
          else
            ppmL[(1 * 9 + k2) * 32 + nloc] = (float)(xx - 1 + (k2 - (k2 / 3) * 3)) + s;
        } else {
          ppmL[(2 * 9 + (j - 18)) * 32 + nloc] = 1.f / (1.f + __expf(-s));
        }
      }
    }
  }
  __syncthreads();

  // ---------- gather helper: fill bsBuf with cols[n0..n0+32][k*256..+256] ----------
  auto gather_k = [&](int kk, uint16_t* bsBuf) {
#pragma unroll
    for (int i = 0; i < 4; ++i) {
      int nloc = wv * 4 + i;
      float py = ppmL[(0 * 9 + kk) * 32 + nloc];
      float px = ppmL[(1 * 9 + kk) * 32 + nloc];
      float mk = ppmL[(2 * 9 + kk) * 32 + nloc];

      float fy0 = floorf(py), fx0 = floorf(px);
      float ly = py - fy0, lx = px - fx0;
      int y0 = (int)fy0, x0 = (int)fx0;
      bool vy0 = ((unsigned)y0 < 64u), vy1 = ((unsigned)(y0 + 1) < 64u);
      bool vx0 = ((unsigned)x0 < 64u), vx1 = ((unsigned)(x0 + 1) < 64u);
      float w00 = (vy0 && vx0) ? (1.f - ly) * (1.f - lx) * mk : 0.f;
      float w01 = (vy0 && vx1) ? (1.f - ly) * lx * mk : 0.f;
      float w10 = (vy1 && vx0) ? ly * (1.f - lx) * mk : 0.f;
      float w11 = (vy1 && vx1) ? ly * lx * mk : 0.f;
      bool sel0 = (x0 >= 63);
      bool sel1 = (x0 >= 0);
      float wa0 = (sel0 ? 0.f : w00) + (sel1 ? 0.f : w01);
      float wb0 = (sel0 ? w00 : 0.f) + (sel1 ? w01 : 0.f);
      float wa1 = (sel0 ? 0.f : w10) + (sel1 ? 0.f : w11);
      float wb1 = (sel0 ? w10 : 0.f) + (sel1 ? w11 : 0.f);
      int bx0 = min(max(x0, 0), 62);
      int a0 = min(max(y0, 0), 63) * 64 + bx0;
      int a1 = min(max(y0 + 1, 0), 63) * 64 + bx0;

      int nn = n0 + nloc;
      const uint16_t* xb2 = xT + ((size_t)(nn >> 12) << 20);
      bf16x4 r00 = *(const bf16x4*)&xb2[a0 * 256 + lane * 4];
      bf16x4 r01 = *(const bf16x4*)&xb2[a0 * 256 + 256 + lane * 4];
      bf16x4 r10 = *(const bf16x4*)&xb2[a1 * 256 + lane * 4];
      bf16x4 r11 = *(const bf16x4*)&xb2[a1 * 256 + 256 + lane * 4];

      float v[4];
#pragma unroll
      for (int s = 0; s < 4; ++s)
        v[s] = wa0 * (float)r00[s] + wb0 * (float)r01[s] +
               wa1 * (float)r10[s] + wb1 * (float)r11[s];

      uint2 pk;
      pk.x = pk_bf16(v[0], v[1]);
      pk.y = pk_bf16(v[2], v[3]);
      *(uint2*)&bsBuf[nloc * 264 + lane * 4] = pk;
    }
  };

  // ---------- main loop: double-buffered gather + MFMA ----------
  f32x4 accO[2][2];
  const f32x4 zero = {0.f, 0.f, 0.f, 0.f};
#pragma unroll
  for (int i = 0; i < 2; ++i)
#pragma unroll
    for (int j = 0; j < 2; ++j) accO[i][j] = zero;

  const uint16_t* apb = wb + (wv * 32 + lr) * CK;

  gather_k(0, Bs2[0]);
  __syncthreads();

  for (int k = 0; k < 9; ++k) {
    if (k < 8) gather_k(k + 1, Bs2[(k + 1) & 1]);
    const uint16_t* ap0 = apb + k * 256 + q * 8;
    const uint16_t* bsb = Bs2[k & 1];
#pragma unroll
    for (int kt = 0; kt < 8; ++kt) {
      int c0 = kt * 32;
      bf16x8 a0 = *(const bf16x8*)&ap0[c0];
      bf16x8 a1 = *(const bf16x8*)&ap0[16 * CK + c0];
#pragma unroll
      for (int j = 0; j < 2; ++j) {
        bf16x8 bF = *(const bf16x8*)&bsb[(j * 16 + lr) * 264 + c0 + q * 8];
        accO[0][j] = __builtin_amdgcn_mfma_f32_16x16x32_bf16(a0, bF, accO[0][j], 0, 0, 0);
        accO[1][j] = __builtin_amdgcn_mfma_f32_16x16x32_bf16(a1, bF, accO[1][j], 0, 0, 0);
      }
    }
    __syncthreads();
  }

  // ---------- epilogue: bias + store ----------
  int bb = n0 >> 12;
  int hw0 = n0 & 4095;
#pragma unroll
  for (int i = 0; i < 2; ++i) {
#pragma unroll
    for (int r = 0; r < 4; ++r) {
      int o = wv * 32 + i * 16 + q * 4 + r;
      float bv = bias[o];
      float* orow = out + (bb * O_ + o) * HW + hw0;
#pragma unroll
      for (int j = 0; j < 2; ++j) orow[j * 16 + lr] = accO[i][j][r] + bv;
    }
  }
}

// ================= fallback path (small workspace): fp32 pipeline =============
__global__ void k0_wconv(const float* __restrict__ weight, uint16_t* __restrict__ wb) {
  int idx = blockIdx.x * 256 + threadIdx.x;
  if (idx >= O_ * CK) return;
  int o = idx / CK;
  int rem = idx - o * CK;
  int k = rem >> 8;
  int c = rem & 255;
  wb[idx] = f2bf(weight[(o * C_ + c) * K_ + k]);
}

__global__ void k1_offconv(const float* __restrict__ x, const float* __restrict__ w_om,
                           const float* __restrict__ b_om, float* __restrict__ pypxmk) {
  int bx = blockIdx.x;
  int jq = bx % 7;
  int h = (bx / 7) % H_;
  int b = bx / (7 * H_);
  int t = threadIdx.x;
  int w = t & 63;
  int cs = __builtin_amdgcn_readfirstlane(t >> 6);

  float acc[4] = {0.f, 0.f, 0.f, 0.f};
  const float* xb = x + (b * C_) * HW;

  for (int ci = 0; ci < 64; ++ci) {
    int c = cs * 64 + ci;
    const float* xr = xb + c * HW;
    float xv[3][3];
#pragma unroll
    for (int r = 0; r < 3; ++r) {
      int y = h - 1 + r;
      bool yv = ((unsigned)y < 64u);
#pragma unroll
      for (int dx = 0; dx < 3; ++dx) {
        int xx = w - 1 + dx;
        bool v = yv && ((unsigned)xx < 64u);
        xv[r][dx] = v ? xr[y * 64 + xx] : 0.f;
      }
    }
    const float* wp = w_om + ((jq * 4) * C_ + c) * 9;
#pragma unroll
    for (int jj = 0; jj < 4; ++jj) {
      int j = jq * 4 + jj;
      int jeff = (j < 27) ? jj : 0;
      const float* wj = wp + jeff * (C_ * 9);
      float a = 0.f;
#pragma unroll
      for (int r = 0; r < 3; ++r)
#pragma unroll
        for (int dx = 0; dx < 3; ++dx)
          a = fmaf(xv[r][dx], wj[r * 3 + dx], a);
      acc[jj] += a;
    }
  }

  __shared__ float red[4][4][64];
#pragma unroll
  for (int jj = 0; jj < 4; ++jj) red[cs][jj][w] = acc[jj];
  __syncthreads();

  int jj = t >> 6;
  int j = jq * 4 + jj;
  if (j < 27) {
    float s = red[0][jj][w] + red[1][jj][w] + red[2][jj][w] + red[3][jj][w] + b_om[j];
    float* pyA = pypxmk;
    float* pxA = pypxmk + 147456;
    float* mkA = pypxmk + 294912;
    if (j < 18) {
      int k = j >> 1;
      int off = (b * 9 + k) * HW + h * 64 + w;
      if ((j & 1) == 0)
        pyA[off] = (float)(h - 1 + k / 3) + s;
      else
        pxA[off] = (float)(w - 1 + k % 3) + s;
    } else {
      int k = j - 18;
      mkA[(b * 9 + k) * HW + h * 64 + w] = 1.f / (1.f + __expf(-s));
    }
  }
}

__global__ void k2_fb(const float* __restrict__ x, const float* __restrict__ pypxmk,
                      uint16_t* __restrict__ cols) {
  int bx = blockIdx.x;
  int cg = bx & 15;
  int h = (bx >> 4) & 63;
  int b = bx >> 10;
  int t = threadIdx.x;
  int w = t & 63;
  int g = t >> 6;

  const float* pyA = pypxmk;
  const float* pxA = pypxmk + 147456;
  const float* mkA = pypxmk + 294912;

  __shared__ uint16_t tile[64 * 146];
  const float* xb = x + b * C_ * HW;
  int cbase = cg * 16 + g * 4;

#pragma unroll
  for (int k = 0; k < 9; ++k) {
    int poff = (b * 9 + k) * HW + h * 64 + w;
    float py = pyA[poff];
    float px = pxA[poff];
    float mk = mkA[poff];
    float fy0 = floorf(py), fx0 = floorf(px);
    float ly = py - fy0, lx = px - fx0;
    int y0 = (int)fy0, x0 = (int)fx0;
    bool vy0 = ((unsigned)y0 < 64u), vy1 = ((unsigned)(y0 + 1) < 64u);
    bool vx0 = ((unsigned)x0 < 64u), vx1 = ((unsigned)(x0 + 1) < 64u);
    float w00 = (vy0 && vx0) ? (1.f - ly) * (1.f - lx) * mk : 0.f;
    float w01 = (vy0 && vx1) ? (1.f - ly) * lx * mk : 0.f;
    float w10 = (vy1 && vx0) ? ly * (1.f - lx) * mk : 0.f;
    float w11 = (vy1 && vx1) ? ly * lx * mk : 0.f;
    bool sel0 = (x0 >= 63);
    bool sel1 = (x0 >= 0);
    float wa0 = (sel0 ? 0.f : w00) + (sel1 ? 0.f : w01);
    float wb0 = (sel0 ? w00 : 0.f) + (sel1 ? w01 : 0.f);
    float wa1 = (sel0 ? 0.f : w10) + (sel1 ? 0.f : w11);
    float wb1 = (sel0 ? w10 : 0.f) + (sel1 ? w11 : 0.f);
    int bx0 = min(max(x0, 0), 62);
    int a0 = min(max(y0, 0), 63) * 64 + bx0;
    int a1 = min(max(y0 + 1, 0), 63) * 64 + bx0;

#pragma unroll
    for (int cp = 0; cp < 2; ++cp) {
      const float* xcA = xb + (cbase + cp * 2) * HW;
      const float* xcB = xcA + HW;
      f32x2 A0 = *(const f32x2u*)&xcA[a0];
      f32x2 A1 = *(const f32x2u*)&xcA[a1];
      f32x2 B0 = *(const f32x2u*)&xcB[a0];
      f32x2 B1 = *(const f32x2u*)&xcB[a1];
      float rA = wa0 * A0.x + wb0 * A0.y + wa1 * A1.x + wb1 * A1.y;
      float rB = wa0 * B0.x + wb0 * B0.y + wa1 * B1.x + wb1 * B1.y;
      *(uint32_t*)&tile[w * 146 + k * 16 + g * 4 + cp * 2] = pk_bf16(rA, rB);
    }
  }
  __syncthreads();

#pragma unroll
  for (int it = 0; it < 18; ++it) {
    int u = t + it * 256;
    int wu = u / 72;
    int rem = u - wu * 72;
    int k = rem >> 3;
    int cd = rem & 7;
    uint32_t val = *(const uint32_t*)&tile[wu * 146 + rem * 2];
    int n = b * HW + h * 64 + wu;
    int dst = n * CK + k * 256 + cg * 16 + cd * 2;
    *(uint32_t*)&cols[dst] = val;
  }
}

__global__ void k3_flex(const uint16_t* __restrict__ wb, const uint16_t* __restrict__ cols,
                        const float* __restrict__ bias, float* __restrict__ out) {
  int bx = blockIdx.x;
  int mt = bx & 1;
  int nt = bx >> 1;
  int o0 = mt * 128;
  int n0 = nt * 128;
  int t = threadIdx.x;
  int lane = t & 63;
  int wid = t >> 6;
  int wm = wid >> 1, wn = wid & 1;
  int lr = lane & 15, q = lane >> 4;

  __shared__ __align__(16) uint16_t As[128 * 32];
  __shared__ __align__(16) uint16_t Bs[128 * 32];

  f32x4 acc[4][4];
  const f32x4 zero = {0.f, 0.f, 0.f, 0.f};
#pragma unroll
  for (int i = 0; i < 4; ++i)
#pragma unroll
    for (int j = 0; j < 4; ++j) acc[i][j] = zero;

  int r0 = t >> 2;
  int koff = (t & 3) * 8;
  const uint16_t* gA = wb + (o0 + r0) * CK + koff;
  const uint16_t* gB = cols + (n0 + r0) * CK + koff;

  for (int kt = 0; kt < 72; ++kt) {
    int k0 = kt * 32;
    __builtin_amdgcn_global_load_lds(
        (const __attribute__((address_space(1))) uint32_t*)(gA + k0),
        (__attribute__((address_space(3))) uint32_t*)&As[t * 8], 16, 0, 0);
    __builtin_amdgcn_global_load_lds(
        (const __attribute__((address_space(1))) uint32_t*)(gA + 64 * CK + k0),
        (__attribute__((address_space(3))) uint32_t*)&As[2048 + t * 8], 16, 0, 0);
    __builtin_amdgcn_global_load_lds(
        (const __attribute__((address_space(1))) uint32_t*)(gB + k0),
        (__attribute__((address_space(3))) uint32_t*)&Bs[t * 8], 16, 0, 0);
    __builtin_amdgcn_global_load_lds(
        (const __attribute__((address_space(1))) uint32_t*)(gB + 64 * CK + k0),
        (__attribute__((address_space(3))) uint32_t*)&Bs[2048 + t * 8], 16, 0, 0);
    __syncthreads();

    bf16x8 aF[4], bF[4];
#pragma unroll
    for (int i = 0; i < 4; ++i)
      aF[i] = *(const bf16x8*)&As[(wm * 64 + i * 16 + lr) * 32 + q * 8];
#pragma unroll
    for (int j = 0; j < 4; ++j)
      bF[j] = *(const bf16x8*)&Bs[(wn * 64 + j * 16 + lr) * 32 + q * 8];
#pragma unroll
    for (int i = 0; i < 4; ++i)
#pragma unroll
      for (int j = 0; j < 4; ++j)
        acc[i][j] = __builtin_amdgcn_mfma_f32_16x16x32_bf16(aF[i], bF[j], acc[i][j], 0, 0, 0);
    __syncthreads();
  }

  int bb = n0 >> 12;
  int hw0 = n0 & 4095;
#pragma unroll
  for (int i = 0; i < 4; ++i) {
#pragma unroll
    for (int r = 0; r < 4; ++r) {
      int o = o0 + wm * 64 + i * 16 + q * 4 + r;
      float bv = bias[o];
      float* orow = out + (bb * O_ + o) * HW + hw0;
#pragma unroll
      for (int j = 0; j < 4; ++j) orow[wn * 64 + j * 16 + lr] = acc[i][j][r] + bv;
    }
  }
}

extern "C" void kernel_launch(void* const* d_in, const int* in_sizes, int n_in,
                              void* d_out, int out_size, void* d_ws, size_t ws_size,
                              hipStream_t stream) {
  const float* x = (const float*)d_in[0];
  const float* w_om = (const float*)d_in[1];
  const float* b_om = (const float*)d_in[2];
  const float* weight = (const float*)d_in[3];
  const float* bias = (const float*)d_in[4];
  float* out = (float*)d_out;

  char* ws = (char*)d_ws;
  uint16_t* wb = (uint16_t*)ws;                 // 1,179,648 B
  uint16_t* womb = (uint16_t*)(ws + 1179648);   // 147,456 B   -> 1,327,104
  uint16_t* xT = (uint16_t*)(ws + 1327104);     // 8,388,608 B -> 9,715,712

  if (ws_size >= 9715712ull) {
    // 2-dispatch pipeline: prep -> fused offset-conv/gather/GEMM
    hipLaunchKernelGGL(kA_prep, dim3(3616), dim3(256), 0, stream, weight, w_om, x, wb, womb, xT);
    hipLaunchKernelGGL(kFused, dim3(512), dim3(512), 0, stream, wb, womb, xT, b_om, bias, out);
  } else {
    // fallback: fp32 pipeline + single-pass GEMM (needs 78.4 MB)
    float* pypx_fb = (float*)(ws + 1179648);
    uint16_t* colsf = (uint16_t*)(ws + 2949120);
    hipLaunchKernelGGL(k0_wconv, dim3(2304), dim3(256), 0, stream, weight, wb);
    hipLaunchKernelGGL(k1_offconv, dim3(4 * 64 * 7), dim3(256), 0, stream, x, w_om, b_om, pypx_fb);
    hipLaunchKernelGGL(k2_fb, dim3(4 * 64 * 16), dim3(256), 0, stream, x, pypx_fb, colsf);
    hipLaunchKernelGGL(k3_flex, dim3(256), dim3(256), 0, stream, wb, colsf, bias, out);
  }
}

// Round 10
// 173.172 us; speedup vs baseline: 1.1250x; 1.1250x over previous
//
#include <hip/hip_runtime.h>
#include <stdint.h>

#define B_ 4
#define C_ 256
#define H_ 64
#define W_ 64
#define O_ 256
#define K_ 9
#define CK 2304     // K_*C_  (ck = k*256 + c, k-major)
#define HW 4096
#define NTOT 16384  // B_*HW

typedef __bf16 bf16x8 __attribute__((ext_vector_type(8)));
typedef __bf16 bf16x4 __attribute__((ext_vector_type(4)));
typedef float f32x4 __attribute__((ext_vector_type(4)));
typedef float f32x2 __attribute__((ext_vector_type(2)));
typedef f32x2 __attribute__((aligned(4))) f32x2u;

__device__ __forceinline__ uint16_t f2bf(float f) {
  uint32_t u = __builtin_bit_cast(uint32_t, f);
  return (uint16_t)((u + 0x7FFFu + ((u >> 16) & 1u)) >> 16);
}

__device__ __forceinline__ uint32_t pk_bf16(float a, float b) {
  uint16_t lo = __builtin_bit_cast(uint16_t, (__bf16)a);
  uint16_t hi = __builtin_bit_cast(uint16_t, (__bf16)b);
  return (uint32_t)lo | ((uint32_t)hi << 16);
}

// ======== kA: fused prep — wb (2304 blk) | womb (288 blk) | xT transpose (1024 blk) ====
__global__ void kA_prep(const float* __restrict__ weight, const float* __restrict__ w_om,
                        const float* __restrict__ x, uint16_t* __restrict__ wb,
                        uint16_t* __restrict__ womb, uint16_t* __restrict__ xT) {
  int bx = blockIdx.x;
  int t = threadIdx.x;
  if (bx < 2304) {
    int idx = bx * 256 + t;
    int o = idx / CK;
    int rem = idx - o * CK;
    int k = rem >> 8, c = rem & 255;
    wb[idx] = f2bf(weight[(o * C_ + c) * K_ + k]);
  } else if (bx < 2592) {
    int idx = (bx - 2304) * 256 + t;
    int j = idx / CK;
    int ck = idx - j * CK;
    int k = ck >> 8, c = ck & 255;
    womb[idx] = (j < 27) ? f2bf(w_om[(j * 256 + c) * 9 + k]) : (uint16_t)0;
  } else {
    int bxl = bx - 2592;
    int ct = bxl & 3;
    int hwt = (bxl >> 2) & 63;
    int b = bxl >> 8;
    int l = t & 63;
    int cq = t >> 6;

    __shared__ __align__(16) uint16_t tile[64 * 72];

    const float* xb = x + ((b * 256 + ct * 64) * HW) + hwt * 64;
#pragma unroll
    for (int i = 0; i < 16; ++i) {
      int c = cq * 16 + i;
      tile[l * 72 + c] = f2bf(xb[c * HW + l]);
    }
    __syncthreads();

    int hw = t >> 2;
    int c8 = (t & 3) * 8;
    uint16_t* dst = xT + ((size_t)b << 20) + (size_t)(hwt * 64 + hw) * 256 + ct * 64;
    *(uint4*)&dst[c8] = *(const uint4*)&tile[hw * 72 + c8];
    *(uint4*)&dst[c8 + 32] = *(const uint4*)&tile[hw * 72 + c8 + 32];
  }
}

// ======== kB: offset conv MFMA, full-K, epilogue writes pypxmk directly ========
__device__ __forceinline__ void write_om(float v, int j, int n, const float* __restrict__ b_om,
                                         float* __restrict__ pypxmk) {
  if (j >= 27) return;
  float s = v + b_om[j];
  int b = n >> 12, hw = n & 4095;
  int h = hw >> 6, w = hw & 63;
  if (j < 18) {
    int k = j >> 1;
    int off = (b * 9 + k) * HW + hw;
    if ((j & 1) == 0)
      pypxmk[off] = (float)(h - 1 + k / 3) + s;
    else
      pypxmk[147456 + off] = (float)(w - 1 + k % 3) + s;
  } else {
    int k = j - 18;
    pypxmk[294912 + (b * 9 + k) * HW + hw] = 1.f / (1.f + __expf(-s));
  }
}

__global__ void k1_mfma(const uint16_t* __restrict__ womb, const uint16_t* __restrict__ xT,
                        const float* __restrict__ b_om, float* __restrict__ pypxmk) {
  int nt = blockIdx.x;       // 0..255
  int t = threadIdx.x;
  int lane = t & 63;
  int wid = t >> 6;
  int lr = lane & 15, q = lane >> 4;
  int n = nt * 64 + wid * 16 + lr;
  int b = n >> 12;
  int hw = n & 4095;
  int y = hw >> 6, xx = hw & 63;
  const uint16_t* xb = xT + ((size_t)b << 20);
  const uint16_t* zrow = womb + 31 * CK;  // 2304 zeros

  f32x4 acc0 = {0.f, 0.f, 0.f, 0.f};
  f32x4 acc1 = {0.f, 0.f, 0.f, 0.f};

#pragma unroll
  for (int k = 0; k < 9; ++k) {
    int dy = k / 3, dx = k - dy * 3;
    int ny = y + dy - 1, nx = xx + dx - 1;
    bool valid = ((unsigned)ny < 64u) && ((unsigned)nx < 64u);
    int row = (min(max(ny, 0), 63) << 6) + min(max(nx, 0), 63);
    const uint16_t* bp = valid ? (xb + row * 256 + q * 8) : (zrow + q * 8);
    const uint16_t* ap = womb + lr * CK + k * 256 + q * 8;
#pragma unroll
    for (int kt = 0; kt < 8; ++kt) {
      int c0 = kt * 32;
      bf16x8 bF = *(const bf16x8*)&bp[c0];
      bf16x8 aF0 = *(const bf16x8*)&ap[c0];
      bf16x8 aF1 = *(const bf16x8*)&ap[16 * CK + c0];
      acc0 = __builtin_amdgcn_mfma_f32_16x16x32_bf16(aF0, bF, acc0, 0, 0, 0);
      acc1 = __builtin_amdgcn_mfma_f32_16x16x32_bf16(aF1, bF, acc1, 0, 0, 0);
    }
  }

#pragma unroll
  for (int r = 0; r < 4; ++r) {
    write_om(acc0[r], q * 4 + r, n, b_om, pypxmk);
    write_om(acc1[r], 16 + q * 4 + r, n, b_om, pypxmk);
  }
}

// ======== kC: bilinear gather -> cols bf16 [n][k*256+c], uniform-triple prefetch ========
__global__ void k2_cols(const uint16_t* __restrict__ xT, const float* __restrict__ pypxmk,
                        uint16_t* __restrict__ cols) {
  int bx = blockIdx.x;
  int g = __builtin_amdgcn_readfirstlane(threadIdx.x >> 6);
  int lane = threadIdx.x & 63;

  const float* pyA = pypxmk;
  const float* pxA = pypxmk + 147456;
  const float* mkA = pypxmk + 294912;

  float py_c, px_c, mk_c;
  {
    int p = g;
    int pn = p / 9;
    int k = p - pn * 9;
    int n = (bx << 3) + pn;
    int poff = ((n >> 12) * 9 + k) * HW + (n & 4095);
    py_c = pyA[poff];
    px_c = pxA[poff];
    mk_c = mkA[poff];
  }

  for (int it = 0; it < 18; ++it) {
    int p = it * 4 + g;
    int pn = p / 9;
    int k = p - pn * 9;
    int n = (bx << 3) + pn;
    int b = n >> 12;

    float py = py_c, px = px_c, mk = mk_c;
    if (it < 17) {
      int p2 = (it + 1) * 4 + g;
      int pn2 = p2 / 9;
      int k2 = p2 - pn2 * 9;
      int n2 = (bx << 3) + pn2;
      int poff2 = ((n2 >> 12) * 9 + k2) * HW + (n2 & 4095);
      py_c = pyA[poff2];
      px_c = pxA[poff2];
      mk_c = mkA[poff2];
    }

    float fy0 = floorf(py), fx0 = floorf(px);
    float ly = py - fy0, lx = px - fx0;
    int y0 = (int)fy0, x0 = (int)fx0;
    bool vy0 = ((unsigned)y0 < 64u), vy1 = ((unsigned)(y0 + 1) < 64u);
    bool vx0 = ((unsigned)x0 < 64u), vx1 = ((unsigned)(x0 + 1) < 64u);
    float w00 = (vy0 && vx0) ? (1.f - ly) * (1.f - lx) * mk : 0.f;
    float w01 = (vy0 && vx1) ? (1.f - ly) * lx * mk : 0.f;
    float w10 = (vy1 && vx0) ? ly * (1.f - lx) * mk : 0.f;
    float w11 = (vy1 && vx1) ? ly * lx * mk : 0.f;
    bool sel0 = (x0 >= 63);
    bool sel1 = (x0 >= 0);
    float wa0 = (sel0 ? 0.f : w00) + (sel1 ? 0.f : w01);
    float wb0 = (sel0 ? w00 : 0.f) + (sel1 ? w01 : 0.f);
    float wa1 = (sel0 ? 0.f : w10) + (sel1 ? 0.f : w11);
    float wb1 = (sel0 ? w10 : 0.f) + (sel1 ? w11 : 0.f);
    int bx0 = min(max(x0, 0), 62);
    int a0 = min(max(y0, 0), 63) * 64 + bx0;
    int a1 = min(max(y0 + 1, 0), 63) * 64 + bx0;

    const uint16_t* xb = xT + ((size_t)b << 20);
    bf16x4 r00 = *(const bf16x4*)&xb[a0 * 256 + lane * 4];
    bf16x4 r01 = *(const bf16x4*)&xb[a0 * 256 + 256 + lane * 4];
    bf16x4 r10 = *(const bf16x4*)&xb[a1 * 256 + lane * 4];
    bf16x4 r11 = *(const bf16x4*)&xb[a1 * 256 + 256 + lane * 4];

    float v[4];
#pragma unroll
    for (int i = 0; i < 4; ++i)
      v[i] = wa0 * (float)r00[i] + wb0 * (float)r01[i] +
             wa1 * (float)r10[i] + wb1 * (float)r11[i];

    uint2 pk;
    pk.x = pk_bf16(v[0], v[1]);
    pk.y = pk_bf16(v[2], v[3]);
    *(uint2*)&cols[(size_t)n * CK + k * 256 + lane * 4] = pk;
  }
}

// ======== kD: single-pass GEMM out = wb . cols + bias; BM=128, BN=64, grid 512 ========
__global__ void k3_gemm(const uint16_t* __restrict__ wb, const uint16_t* __restrict__ cols,
                        const float* __restrict__ bias, float* __restrict__ out) {
  int bx = blockIdx.x;
  int mt = bx & 1;
  int nt = bx >> 1;          // 0..255
  int o0 = mt * 128;
  int n0 = nt * 64;
  int t = threadIdx.x;
  int lane = t & 63;
  int wid = t >> 6;
  int wm = wid >> 1, wn = wid & 1;
  int lr = lane & 15, q = lane >> 4;

  __shared__ __align__(16) uint16_t As[128 * 32];
  __shared__ __align__(16) uint16_t Bs[64 * 32];

  f32x4 acc[4][2];
  const f32x4 zero = {0.f, 0.f, 0.f, 0.f};
#pragma unroll
  for (int i = 0; i < 4; ++i)
#pragma unroll
    for (int j = 0; j < 2; ++j) acc[i][j] = zero;

  int r0 = t >> 2;          // 0..63
  int koff = (t & 3) * 8;
  const uint16_t* gA = wb + (o0 + r0) * CK + koff;
  const uint16_t* gB = cols + (n0 + r0) * CK + koff;

  for (int kt = 0; kt < 72; ++kt) {
    int k0 = kt * 32;
    __builtin_amdgcn_global_load_lds(
        (const __attribute__((address_space(1))) uint32_t*)(gA + k0),
        (__attribute__((address_space(3))) uint32_t*)&As[t * 8], 16, 0, 0);
    __builtin_amdgcn_global_load_lds(
        (const __attribute__((address_space(1))) uint32_t*)(gA + 64 * CK + k0),
        (__attribute__((address_space(3))) uint32_t*)&As[2048 + t * 8], 16, 0, 0);
    __builtin_amdgcn_global_load_lds(
        (const __attribute__((address_space(1))) uint32_t*)(gB + k0),
        (__attribute__((address_space(3))) uint32_t*)&Bs[t * 8], 16, 0, 0);
    __syncthreads();

    bf16x8 aF[4], bF[2];
#pragma unroll
    for (int i = 0; i < 4; ++i)
      aF[i] = *(const bf16x8*)&As[(wm * 64 + i * 16 + lr) * 32 + q * 8];
#pragma unroll
    for (int j = 0; j < 2; ++j)
      bF[j] = *(const bf16x8*)&Bs[(wn * 32 + j * 16 + lr) * 32 + q * 8];
#pragma unroll
    for (int i = 0; i < 4; ++i)
#pragma unroll
      for (int j = 0; j < 2; ++j)
        acc[i][j] = __builtin_amdgcn_mfma_f32_16x16x32_bf16(aF[i], bF[j], acc[i][j], 0, 0, 0);
    __syncthreads();
  }

  int bb = n0 >> 12;
  int hw0 = n0 & 4095;
#pragma unroll
  for (int i = 0; i < 4; ++i) {
#pragma unroll
    for (int r = 0; r < 4; ++r) {
      int o = o0 + wm * 64 + i * 16 + q * 4 + r;
      float bv = bias[o];
      float* orow = out + (bb * O_ + o) * HW + hw0;
#pragma unroll
      for (int j = 0; j < 2; ++j) orow[wn * 32 + j * 16 + lr] = acc[i][j][r] + bv;
    }
  }
}

// ================= fallback path (small workspace): fp32 pipeline =============
__global__ void k0_wconv(const float* __restrict__ weight, uint16_t* __restrict__ wb) {
  int idx = blockIdx.x * 256 + threadIdx.x;
  if (idx >= O_ * CK) return;
  int o = idx / CK;
  int rem = idx - o * CK;
  int k = rem >> 8;
  int c = rem & 255;
  wb[idx] = f2bf(weight[(o * C_ + c) * K_ + k]);
}

__global__ void k1_offconv(const float* __restrict__ x, const float* __restrict__ w_om,
                           const float* __restrict__ b_om, float* __restrict__ pypxmk) {
  int bx = blockIdx.x;
  int jq = bx % 7;
  int h = (bx / 7) % H_;
  int b = bx / (7 * H_);
  int t = threadIdx.x;
  int w = t & 63;
  int cs = __builtin_amdgcn_readfirstlane(t >> 6);

  float acc[4] = {0.f, 0.f, 0.f, 0.f};
  const float* xb = x + (b * C_) * HW;

  for (int ci = 0; ci < 64; ++ci) {
    int c = cs * 64 + ci;
    const float* xr = xb + c * HW;
    float xv[3][3];
#pragma unroll
    for (int r = 0; r < 3; ++r) {
      int y = h - 1 + r;
      bool yv = ((unsigned)y < 64u);
#pragma unroll
      for (int dx = 0; dx < 3; ++dx) {
        int xx = w - 1 + dx;
        bool v = yv && ((unsigned)xx < 64u);
        xv[r][dx] = v ? xr[y * 64 + xx] : 0.f;
      }
    }
    const float* wp = w_om + ((jq * 4) * C_ + c) * 9;
#pragma unroll
    for (int jj = 0; jj < 4; ++jj) {
      int j = jq * 4 + jj;
      int jeff = (j < 27) ? jj : 0;
      const float* wj = wp + jeff * (C_ * 9);
      float a = 0.f;
#pragma unroll
      for (int r = 0; r < 3; ++r)
#pragma unroll
        for (int dx = 0; dx < 3; ++dx)
          a = fmaf(xv[r][dx], wj[r * 3 + dx], a);
      acc[jj] += a;
    }
  }

  __shared__ float red[4][4][64];
#pragma unroll
  for (int jj = 0; jj < 4; ++jj) red[cs][jj][w] = acc[jj];
  __syncthreads();

  int jj = t >> 6;
  int j = jq * 4 + jj;
  if (j < 27) {
    float s = red[0][jj][w] + red[1][jj][w] + red[2][jj][w] + red[3][jj][w] + b_om[j];
    float* pyA = pypxmk;
    float* pxA = pypxmk + 147456;
    float* mkA = pypxmk + 294912;
    if (j < 18) {
      int k = j >> 1;
      int off = (b * 9 + k) * HW + h * 64 + w;
      if ((j & 1) == 0)
        pyA[off] = (float)(h - 1 + k / 3) + s;
      else
        pxA[off] = (float)(w - 1 + k % 3) + s;
    } else {
      int k = j - 18;
      mkA[(b * 9 + k) * HW + h * 64 + w] = 1.f / (1.f + __expf(-s));
    }
  }
}

__global__ void k2_fb(const float* __restrict__ x, const float* __restrict__ pypxmk,
                      uint16_t* __restrict__ cols) {
  int bx = blockIdx.x;
  int cg = bx & 15;
  int h = (bx >> 4) & 63;
  int b = bx >> 10;
  int t = threadIdx.x;
  int w = t & 63;
  int g = t >> 6;

  const float* pyA = pypxmk;
  const float* pxA = pypxmk + 147456;
  const float* mkA = pypxmk + 294912;

  __shared__ uint16_t tile[64 * 146];
  const float* xb = x + b * C_ * HW;
  int cbase = cg * 16 + g * 4;

#pragma unroll
  for (int k = 0; k < 9; ++k) {
    int poff = (b * 9 + k) * HW + h * 64 + w;
    float py = pyA[poff];
    float px = pxA[poff];
    float mk = mkA[poff];
    float fy0 = floorf(py), fx0 = floorf(px);
    float ly = py - fy0, lx = px - fx0;
    int y0 = (int)fy0, x0 = (int)fx0;
    bool vy0 = ((unsigned)y0 < 64u), vy1 = ((unsigned)(y0 + 1) < 64u);
    bool vx0 = ((unsigned)x0 < 64u), vx1 = ((unsigned)(x0 + 1) < 64u);
    float w00 = (vy0 && vx0) ? (1.f - ly) * (1.f - lx) * mk : 0.f;
    float w01 = (vy0 && vx1) ? (1.f - ly) * lx * mk : 0.f;
    float w10 = (vy1 && vx0) ? ly * (1.f - lx) * mk : 0.f;
    float w11 = (vy1 && vx1) ? ly * lx * mk : 0.f;
    bool sel0 = (x0 >= 63);
    bool sel1 = (x0 >= 0);
    float wa0 = (sel0 ? 0.f : w00) + (sel1 ? 0.f : w01);
    float wb0 = (sel0 ? w00 : 0.f) + (sel1 ? w01 : 0.f);
    float wa1 = (sel0 ? 0.f : w10) + (sel1 ? 0.f : w11);
    float wb1 = (sel0 ? w10 : 0.f) + (sel1 ? w11 : 0.f);
    int bx0 = min(max(x0, 0), 62);
    int a0 = min(max(y0, 0), 63) * 64 + bx0;
    int a1 = min(max(y0 + 1, 0), 63) * 64 + bx0;

#pragma unroll
    for (int cp = 0; cp < 2; ++cp) {
      const float* xcA = xb + (cbase + cp * 2) * HW;
      const float* xcB = xcA + HW;
      f32x2 A0 = *(const f32x2u*)&xcA[a0];
      f32x2 A1 = *(const f32x2u*)&xcA[a1];
      f32x2 B0 = *(const f32x2u*)&xcB[a0];
      f32x2 B1 = *(const f32x2u*)&xcB[a1];
      float rA = wa0 * A0.x + wb0 * A0.y + wa1 * A1.x + wb1 * A1.y;
      float rB = wa0 * B0.x + wb0 * B0.y + wa1 * B1.x + wb1 * B1.y;
      *(uint32_t*)&tile[w * 146 + k * 16 + g * 4 + cp * 2] = pk_bf16(rA, rB);
    }
  }
  __syncthreads();

#pragma unroll
  for (int it = 0; it < 18; ++it) {
    int u = t + it * 256;
    int wu = u / 72;
    int rem = u - wu * 72;
    int k = rem >> 3;
    int cd = rem & 7;
    uint32_t val = *(const uint32_t*)&tile[wu * 146 + rem * 2];
    int n = b * HW + h * 64 + wu;
    int dst = n * CK + k * 256 + cg * 16 + cd * 2;
    *(uint32_t*)&cols[dst] = val;
  }
}

__global__ void k3_flex(const uint16_t* __restrict__ wb, const uint16_t* __restrict__ cols,
                        const float* __restrict__ bias, float* __restrict__ out) {
  int bx = blockIdx.x;
  int mt = bx & 1;
  int nt = bx >> 1;
  int o0 = mt * 128;
  int n0 = nt * 128;
  int t = threadIdx.x;
  int lane = t & 63;
  int wid = t >> 6;
  int wm = wid >> 1, wn = wid & 1;
  int lr = lane & 15, q = lane >> 4;

  __shared__ __align__(16) uint16_t As[128 * 32];
  __shared__ __align__(16) uint16_t Bs[128 * 32];

  f32x4 acc[4][4];
  const f32x4 zero = {0.f, 0.f, 0.f, 0.f};
#pragma unroll
  for (int i = 0; i < 4; ++i)
#pragma unroll
    for (int j = 0; j < 4; ++j) acc[i][j] = zero;

  int r0 = t >> 2;
  int koff = (t & 3) * 8;
  const uint16_t* gA = wb + (o0 + r0) * CK + koff;
  const uint16_t* gB = cols + (n0 + r0) * CK + koff;

  for (int kt = 0; kt < 72; ++kt) {
    int k0 = kt * 32;
    __builtin_amdgcn_global_load_lds(
        (const __attribute__((address_space(1))) uint32_t*)(gA + k0),
        (__attribute__((address_space(3))) uint32_t*)&As[t * 8], 16, 0, 0);
    __builtin_amdgcn_global_load_lds(
        (const __attribute__((address_space(1))) uint32_t*)(gA + 64 * CK + k0),
        (__attribute__((address_space(3))) uint32_t*)&As[2048 + t * 8], 16, 0, 0);
    __builtin_amdgcn_global_load_lds(
        (const __attribute__((address_space(1))) uint32_t*)(gB + k0),
        (__attribute__((address_space(3))) uint32_t*)&Bs[t * 8], 16, 0, 0);
    __builtin_amdgcn_global_load_lds(
        (const __attribute__((address_space(1))) uint32_t*)(gB + 64 * CK + k0),
        (__attribute__((address_space(3))) uint32_t*)&Bs[2048 + t * 8], 16, 0, 0);
    __syncthreads();

    bf16x8 aF[4], bF[4];
#pragma unroll
    for (int i = 0; i < 4; ++i)
      aF[i] = *(const bf16x8*)&As[(wm * 64 + i * 16 + lr) * 32 + q * 8];
#pragma unroll
    for (int j = 0; j < 4; ++j)
      bF[j] = *(const bf16x8*)&Bs[(wn * 64 + j * 16 + lr) * 32 + q * 8];
#pragma unroll
    for (int i = 0; i < 4; ++i)
#pragma unroll
      for (int j = 0; j < 4; ++j)
        acc[i][j] = __builtin_amdgcn_mfma_f32_16x16x32_bf16(aF[i], bF[j], acc[i][j], 0, 0, 0);
    __syncthreads();
  }

  int bb = n0 >> 12;
  int hw0 = n0 & 4095;
#pragma unroll
  for (int i = 0; i < 4; ++i) {
#pragma unroll
    for (int r = 0; r < 4; ++r) {
      int o = o0 + wm * 64 + i * 16 + q * 4 + r;
      float bv = bias[o];
      float* orow = out + (bb * O_ + o) * HW + hw0;
#pragma unroll
      for (int j = 0; j < 4; ++j) orow[wn * 64 + j * 16 + lr] = acc[i][j][r] + bv;
    }
  }
}

extern "C" void kernel_launch(void* const* d_in, const int* in_sizes, int n_in,
                              void* d_out, int out_size, void* d_ws, size_t ws_size,
                              hipStream_t stream) {
  const float* x = (const float*)d_in[0];
  const float* w_om = (const float*)d_in[1];
  const float* b_om = (const float*)d_in[2];
  const float* weight = (const float*)d_in[3];
  const float* bias = (const float*)d_in[4];
  float* out = (float*)d_out;

  char* ws = (char*)d_ws;
  uint16_t* wb = (uint16_t*)ws;                   // 1,179,648 B
  uint16_t* womb = (uint16_t*)(ws + 1179648);     // 147,456 B    -> 1,327,104
  uint16_t* xT = (uint16_t*)(ws + 1327104);       // 8,388,608 B  -> 9,715,712
  float* pypxmk = (float*)(ws + 9715712);         // 1,769,472 B  -> 11,485,184
  uint16_t* cols = (uint16_t*)(ws + 11485184);    // 75,497,472 B -> 86,982,656

  if (ws_size >= 86982656ull) {
    // 4-dispatch pipeline (r8 structure + single-pass GEMM)
    hipLaunchKernelGGL(kA_prep, dim3(3616), dim3(256), 0, stream, weight, w_om, x, wb, womb, xT);
    hipLaunchKernelGGL(k1_mfma, dim3(256), dim3(256), 0, stream, womb, xT, b_om, pypxmk);
    hipLaunchKernelGGL(k2_cols, dim3(2048), dim3(256), 0, stream, xT, pypxmk, cols);
    hipLaunchKernelGGL(k3_gemm, dim3(512), dim3(256), 0, stream, wb, cols, bias, out);
  } else {
    // fallback: fp32 pipeline + single-pass GEMM (needs 78.4 MB)
    float* pypx_fb = (float*)(ws + 1179648);
    uint16_t* colsf = (uint16_t*)(ws + 2949120);
    hipLaunchKernelGGL(k0_wconv, dim3(2304), dim3(256), 0, stream, weight, wb);
    hipLaunchKernelGGL(k1_offconv, dim3(4 * 64 * 7), dim3(256), 0, stream, x, w_om, b_om, pypx_fb);
    hipLaunchKernelGGL(k2_fb, dim3(4 * 64 * 16), dim3(256), 0, stream, x, pypx_fb, colsf);
    hipLaunchKernelGGL(k3_flex, dim3(256), dim3(256), 0, stream, wb, colsf, bias, out);
  }
}